// Round 3
// baseline (1281.890 us; speedup 1.0000x reference)
//
#include <hip/hip_runtime.h>
#include <hip/hip_cooperative_groups.h>
#include <stdint.h>

namespace cg = cooperative_groups;

// MST on 128x256 grid, B=4, Boruvka with (weight, eid) total order.
// Single cooperative kernel: keys+init -> [edgemin -> sync -> hook -> sync]*
// -> count -> scan -> write. Weights: f32 L2 over 64 ch, sequential
// __fadd_rn(__fmul_rn) accumulation (bit-matches reference; output is a
// compacted edge list so one flipped comparison shifts the whole tail).

#define HH 128
#define WW 256
#define NN (HH*WW)          // 32768 = 2^15
#define RE ((HH-1)*WW)      // 32512
#define EE (RE + HH*(WW-1)) // 65152
#define BATCH 4
#define CH 64
#define ROUNDS 15           // components at least halve per round; 2^15 = N
#define TPB 256
#define GRID 512
#define EPAD 65536          // padded per-batch edge stride (b<<16 | e)

typedef unsigned long long u64;
typedef unsigned int u32;

__device__ __forceinline__ void edge_uv(int e, int& u, int& v) {
    if (e < RE) { u = e; v = e + WW; }          // row edge (i,j)-(i+1,j)
    else {                                      // col edge (i,j)-(i,j+1)
        int ec = e - RE;
        int i = ec / (WW - 1);
        int j = ec - i * (WW - 1);
        u = i * WW + j; v = u + 1;
    }
}

// per-node hook: pick best edge, 2-cycle iff both roots chose the SAME edge
// (mutual min over the same cut => equal (w,eid)); mark sel; reset other buf.
__device__ __forceinline__ void hook_phase(int tid, const u64* __restrict__ cur,
                                           u64* __restrict__ nxt,
                                           const u32* __restrict__ label,
                                           u32* __restrict__ succ,
                                           u32* __restrict__ sel,
                                           int* __restrict__ flags, int r) {
    int nb = tid >> 15, n = tid & (NN - 1);
    u64 bk = cur[tid];
    u32 s = (u32)n;
    if (bk != ~0ull) {
        int e = (int)(u32)bk;
        int u, v; edge_uv(e, u, v);
        const u32* lab = label + (nb << 15);
        u32 ou = lab[u], ov = lab[v];
        u32 o = (ou == (u32)n) ? ov : ou;
        u64 bko = cur[(nb << 15) + (int)o];
        s = ((u32)bko == (u32)bk && (u32)n < o) ? (u32)n : o;
        sel[(nb << 16) + e] = 1u;               // benign race: same value
        flags[r] = 1;                           // benign race: same value
    }
    succ[tid] = s;
    nxt[tid] = ~0ull;
}

__global__ __launch_bounds__(TPB, 4) void k_mst(
    const float* __restrict__ g, u32* __restrict__ keyw,
    u32* __restrict__ label, u32* __restrict__ succ,
    u64* __restrict__ bestA, u64* __restrict__ bestB,
    u32* __restrict__ sel, int* __restrict__ flags,
    u32* __restrict__ cnt, u32* __restrict__ cbase,
    int* __restrict__ out)
{
    cg::grid_group grid = cg::this_grid();
    const int tid = (int)(blockIdx.x * TPB + threadIdx.x);   // 0..131071
    __shared__ u32 sdata[TPB];
    __shared__ int sflag;

    // thread t owns edge e0 of batches b0 and b0+2, and node tid.
    const int e0 = tid & (EPAD - 1);
    const int b0 = tid >> 16;                   // 0 or 1
    const int b1 = b0 + 2;
    const bool isE = (e0 < EE);
    int eu = 0, ev = 0;
    u32 k0 = 0, k1 = 0;

    // ---- phase 0: keys (kept in regs) + init
    if (isE) {
        edge_uv(e0, eu, ev);
        const float* gb0 = g + (size_t)b0 * CH * NN;
        const float* gb1 = g + (size_t)b1 * CH * NN;
        float a0 = 0.f, a1 = 0.f;
        #pragma unroll 8
        for (int c = 0; c < CH; ++c) {
            float x0 = gb0[(size_t)c * NN + eu] - gb0[(size_t)c * NN + ev];
            float x1 = gb1[(size_t)c * NN + eu] - gb1[(size_t)c * NN + ev];
            a0 = __fadd_rn(a0, __fmul_rn(x0, x0));   // forbid fma contraction
            a1 = __fadd_rn(a1, __fmul_rn(x1, x1));
        }
        k0 = __float_as_uint(sqrtf(a0));
        k1 = __float_as_uint(sqrtf(a1));
        keyw[(b0 << 16) | e0] = k0;
        keyw[(b1 << 16) | e0] = k1;
    }
    {
        u32 n = (u32)(tid & (NN - 1));
        label[tid] = n; succ[tid] = n; bestA[tid] = ~0ull;
    }
    sel[(b0 << 16) | e0] = 0u;
    sel[(b1 << 16) | e0] = 0u;
    if (tid < ROUNDS) flags[tid] = 0;
    grid.sync();

    // ---- round 0 edgemin (identity labels: roots are the endpoints)
    if (isE) {
        u64 kk0 = ((u64)k0 << 32) | (u32)e0;
        u64 kk1 = ((u64)k1 << 32) | (u32)e0;
        atomicMin(bestA + (b0 << 15) + eu, kk0);
        atomicMin(bestA + (b0 << 15) + ev, kk0);
        atomicMin(bestA + (b1 << 15) + eu, kk1);
        atomicMin(bestA + (b1 << 15) + ev, kk1);
    }
    grid.sync();
    hook_phase(tid, bestA, bestB, label, succ, sel, flags, 0);
    grid.sync();                                 // round 0 always active

    // ---- generic rounds
    for (int r = 1; r < ROUNDS; ++r) {
        u64* cur = (r & 1) ? bestB : bestA;
        u64* nxt = (r & 1) ? bestA : bestB;
        if (isE) {
            #pragma unroll
            for (int s2 = 0; s2 < 2; ++s2) {
                int bb = s2 ? b1 : b0;
                const u32* sb = succ + (bb << 15);
                u32* lab = label + (bb << 15);
                u32 ru = lab[eu]; { u32 nx = sb[ru]; while (nx != ru) { ru = nx; nx = sb[ru]; } }
                u32 rv = lab[ev]; { u32 nx = sb[rv]; while (nx != rv) { rv = nx; nx = sb[rv]; } }
                lab[eu] = ru; lab[ev] = rv;      // benign race: same root value
                if (ru != rv) {
                    u64 k = ((u64)keyw[(bb << 16) | e0] << 32) | (u32)e0;
                    atomicMin(cur + (bb << 15) + (int)ru, k);
                    atomicMin(cur + (bb << 15) + (int)rv, k);
                }
            }
        }
        grid.sync();
        hook_phase(tid, cur, nxt, label, succ, sel, flags, r);
        grid.sync();
        if (threadIdx.x == 0) sflag = flags[r];
        __syncthreads();
        if (!sflag) break;                       // uniform across grid
    }

    // ---- compaction: 1024 chunk-tasks (batch b, 256-edge chunk c)
    #pragma unroll
    for (int it = 0; it < 2; ++it) {
        int task = (int)blockIdx.x + it * GRID;
        int tb = task >> 8, tc = task & 255;
        int e = (tc << 8) + (int)threadIdx.x;
        bool f = sel[(tb << 16) + e] != 0u;      // padded area is 0
        u64 m = __ballot(f);
        if ((threadIdx.x & 63) == 0) sdata[threadIdx.x >> 6] = (u32)__popcll(m);
        __syncthreads();
        if (threadIdx.x == 0) cnt[task] = sdata[0] + sdata[1] + sdata[2] + sdata[3];
        __syncthreads();
    }
    grid.sync();
    if (blockIdx.x < BATCH) {                    // scan 256 chunk counts per batch
        int bb = (int)blockIdx.x, i = (int)threadIdx.x;
        u32 vv = cnt[(bb << 8) + i];
        sdata[i] = vv; __syncthreads();
        #pragma unroll
        for (int d = 1; d < 256; d <<= 1) {
            u32 t2 = (i >= d) ? sdata[i - d] : 0u;
            __syncthreads();
            sdata[i] += t2;
            __syncthreads();
        }
        cbase[(bb << 8) + i] = sdata[i] - vv;    // exclusive
    }
    grid.sync();
    #pragma unroll
    for (int it = 0; it < 2; ++it) {
        int task = (int)blockIdx.x + it * GRID;
        int tb = task >> 8, tc = task & 255;
        int e = (tc << 8) + (int)threadIdx.x;
        bool f = sel[(tb << 16) + e] != 0u;
        u64 m = __ballot(f);
        int lane = (int)threadIdx.x & 63, wid = (int)threadIdx.x >> 6;
        if (lane == 0) sdata[wid] = (u32)__popcll(m);
        __syncthreads();
        if (threadIdx.x == 0) {
            u32 acc = cbase[task];
            #pragma unroll
            for (int i2 = 0; i2 < 4; ++i2) { u32 t2 = sdata[i2]; sdata[i2] = acc; acc += t2; }
        }
        __syncthreads();
        if (f) {
            u32 pos = sdata[wid] + (u32)__popcll(m & ((1ull << lane) - 1));
            int u, v; edge_uv(e, u, v);
            int* ob = out + (size_t)tb * (NN - 1) * 2;
            ob[(size_t)pos * 2]     = u;
            ob[(size_t)pos * 2 + 1] = v;
        }
        __syncthreads();
    }
}

extern "C" void kernel_launch(void* const* d_in, const int* in_sizes, int n_in,
                              void* d_out, int out_size, void* d_ws, size_t ws_size,
                              hipStream_t stream) {
    const float* g = (const float*)d_in[0];
    int* out = (int*)d_out;
    char* ws = (char*)d_ws;

    // workspace layout (~5.3 MB), 8B-aligned blocks first
    u64* bestA = (u64*)ws;                                   // B*N*8
    u64* bestB = bestA + (size_t)BATCH * NN;                 // B*N*8
    u32* keyw  = (u32*)(bestB + (size_t)BATCH * NN);         // B*EPAD*4
    u32* label = keyw + (size_t)BATCH * EPAD;                // B*N*4
    u32* succ  = label + (size_t)BATCH * NN;                 // B*N*4
    u32* sel   = succ + (size_t)BATCH * NN;                  // B*EPAD*4
    u32* cnt   = sel + (size_t)BATCH * EPAD;                 // 1024*4
    u32* cbase = cnt + 1024;                                 // 1024*4
    int* flags = (int*)(cbase + 1024);                       // ROUNDS*4

    void* args[] = {(void*)&g, (void*)&keyw, (void*)&label, (void*)&succ,
                    (void*)&bestA, (void*)&bestB, (void*)&sel, (void*)&flags,
                    (void*)&cnt, (void*)&cbase, (void*)&out};
    hipLaunchCooperativeKernel((const void*)k_mst, dim3(GRID), dim3(TPB),
                               args, 0u, stream);
}

// Round 4
// 677.265 us; speedup vs baseline: 1.8927x; 1.8927x over previous
//
#include <hip/hip_runtime.h>
#include <stdint.h>

// MST on 128x256 grid, B=4, Boruvka with (weight, eid) total order.
// k_keys: full-grid weight kernel (bit-exact seq accumulation, no FMA).
// k_mst4: 4 persistent blocks (one per batch), parent/label in LDS (u16),
// best[] in global (own-XCD L2, block-private), edge-centric winner hooking,
// per-thread dead-edge masks, in-block compaction. Zero grid-wide syncs.

#define HH 128
#define WW 256
#define NN (HH*WW)          // 32768 = 2^15
#define RE ((HH-1)*WW)      // 32512
#define EE (RE + HH*(WW-1)) // 65152
#define CH 64
#define ROUNDS 15           // components at least halve per round; 2^15 = N
#define EPAD 65536

typedef unsigned long long u64;
typedef unsigned int u32;
typedef unsigned short u16;

__device__ __forceinline__ void edge_uv(int e, int& u, int& v) {
    if (e < RE) { u = e; v = e + WW; }          // row edge (i,j)-(i+1,j)
    else {                                      // col edge (i,j)-(i,j+1)
        int ec = e - RE;
        int i = ec / (WW - 1);
        int j = ec - i * (WW - 1);
        u = i * WW + j; v = u + 1;
    }
}

// weights for batches {b0, b0+2} per thread; also inits best = ~0
__global__ __launch_bounds__(256) void k_keys(const float* __restrict__ g,
                                              u32* __restrict__ keyw,
                                              u64* __restrict__ best) {
    int t = blockIdx.x * blockDim.x + threadIdx.x;   // 0..131071 == B*N
    best[t] = ~0ull;
    int e0 = t & (EPAD - 1);
    int b0 = t >> 16;                                // 0 or 1
    if (e0 >= EE) return;
    int u, v; edge_uv(e0, u, v);
    const float* gb0 = g + (size_t)b0 * CH * NN;
    const float* gb1 = gb0 + (size_t)2 * CH * NN;
    float a0 = 0.f, a1 = 0.f;
    #pragma unroll 8
    for (int c = 0; c < CH; ++c) {
        float x0 = gb0[(size_t)c * NN + u] - gb0[(size_t)c * NN + v];
        float x1 = gb1[(size_t)c * NN + u] - gb1[(size_t)c * NN + v];
        a0 = __fadd_rn(a0, __fmul_rn(x0, x0));       // forbid fma contraction
        a1 = __fadd_rn(a1, __fmul_rn(x1, x1));
    }
    keyw[(b0 << 16) | e0] = __float_as_uint(sqrtf(a0));
    keyw[((b0 + 2) << 16) | e0] = __float_as_uint(sqrtf(a1));
}

__global__ __launch_bounds__(1024) void k_mst4(const u32* __restrict__ keyw,
                                               u64* __restrict__ best,
                                               int* __restrict__ out) {
    __shared__ u16 par[NN];          // 64 KB
    __shared__ u16 lab[NN];          // 64 KB
    __shared__ u32 selw[EPAD / 32];  // 8 KB edge bitmask
    __shared__ int wsum[32];
    __shared__ int sflag[2];

    const int b = (int)blockIdx.x;
    const int tid = (int)threadIdx.x;
    const u32* kb = keyw + (b << 16);
    u64* bb = best + (b << 15);

    for (int k = tid; k < NN; k += 1024) { par[k] = (u16)k; lab[k] = (u16)k; }
    for (int k = tid; k < EPAD / 32; k += 1024) selw[k] = 0u;
    if (tid == 0) { sflag[0] = 0; sflag[1] = 0; }
    __syncthreads();

    // thread's edge k-bit <-> e = (k<<10)+tid ; k=63 invalid for tid>=640
    u64 dead = (tid >= (EE - 63 * 1024)) ? (1ull << 63) : 0ull;

    for (int r = 0; r < ROUNDS; ++r) {
        // ---- phase A: chase roots, path-compress lab, scatter atomicMin
        u64 act = 0;
        u64 m = ~dead;
        bool any = false;
        while (m) {
            int k = __ffsll((long long)m) - 1;
            m &= m - 1;
            int e = (k << 10) + tid;
            int u, v; edge_uv(e, u, v);
            u32 ru = lab[u]; { u32 p = par[ru]; while (p != ru) { ru = p; p = par[ru]; } }
            u32 rv = lab[v]; { u32 p = par[rv]; while (p != rv) { rv = p; p = par[rv]; } }
            lab[u] = (u16)ru; lab[v] = (u16)rv;      // benign same-value races
            if (ru == rv) { dead |= 1ull << k; continue; }
            any = true;
            act |= 1ull << k;
            u64 key = ((u64)kb[e] << 32) | (u32)e;
            atomicMin(bb + ru, key);                  // fire-and-forget
            atomicMin(bb + rv, key);
        }
        if (any) sflag[r & 1] = 1;
        __syncthreads();                              // drains atomics too
        if (!sflag[r & 1]) break;                     // uniform
        if (tid == 0) sflag[(r + 1) & 1] = 0;
        // ---- phase B+C: unique winner per root hooks it, marks sel, resets best
        while (act) {
            int k = __ffsll((long long)act) - 1;
            act &= act - 1;
            int e = (k << 10) + tid;
            int u, v; edge_uv(e, u, v);
            u32 ru = lab[u], rv = lab[v];             // roots (stable in this phase)
            u64 bu = __hip_atomic_load(bb + ru, __ATOMIC_RELAXED, __HIP_MEMORY_SCOPE_AGENT);
            u64 bv = __hip_atomic_load(bb + rv, __ATOMIC_RELAXED, __HIP_MEMORY_SCOPE_AGENT);
            bool wU = ((u32)bu == (u32)e);            // reset low32=0xFFFFFFFF can't match
            bool wV = ((u32)bv == (u32)e);
            if (wU | wV) {
                atomicOr(&selw[e >> 5], 1u << (e & 31));
                if (wU & wV) {                        // mutual min: max hooks to min
                    u32 mn = ru < rv ? ru : rv, mx = ru < rv ? rv : ru;
                    par[mx] = (u16)mn;
                    __hip_atomic_store(bb + ru, ~0ull, __ATOMIC_RELAXED, __HIP_MEMORY_SCOPE_AGENT);
                    __hip_atomic_store(bb + rv, ~0ull, __ATOMIC_RELAXED, __HIP_MEMORY_SCOPE_AGENT);
                } else if (wU) {
                    par[ru] = (u16)rv;
                    __hip_atomic_store(bb + ru, ~0ull, __ATOMIC_RELAXED, __HIP_MEMORY_SCOPE_AGENT);
                } else {
                    par[rv] = (u16)ru;
                    __hip_atomic_store(bb + rv, ~0ull, __ATOMIC_RELAXED, __HIP_MEMORY_SCOPE_AGENT);
                }
            }
        }
        __syncthreads();
    }

    // ---- in-block stable compaction from LDS bitmask (thread owns 64 eids)
    u32 w0 = selw[tid * 2], w1 = selw[tid * 2 + 1];
    int cnt = __popc(w0) + __popc(w1);
    int lane = tid & 63, wid = tid >> 6;
    int inc = cnt;
    #pragma unroll
    for (int d = 1; d < 64; d <<= 1) {
        int t2 = __shfl_up(inc, d, 64);
        if (lane >= d) inc += t2;
    }
    if (lane == 63) wsum[wid] = inc;
    __syncthreads();
    if (tid < 16) {
        int vv = wsum[tid];
        int inc2 = vv;
        #pragma unroll
        for (int d = 1; d < 16; d <<= 1) {
            int t2 = __shfl_up(inc2, d, 16);
            if (tid >= d) inc2 += t2;
        }
        wsum[tid] = inc2 - vv;                        // exclusive wave base
    }
    __syncthreads();
    int pos = wsum[wid] + inc - cnt;
    int* ob = out + (size_t)b * (NN - 1) * 2;
    u64 bits = ((u64)w1 << 32) | (u64)w0;
    while (bits) {
        int bi = __ffsll((long long)bits) - 1;
        bits &= bits - 1;
        int e = (tid << 6) + bi;
        int u, v; edge_uv(e, u, v);
        ob[(size_t)pos * 2] = u;
        ob[(size_t)pos * 2 + 1] = v;
        ++pos;
    }
}

extern "C" void kernel_launch(void* const* d_in, const int* in_sizes, int n_in,
                              void* d_out, int out_size, void* d_ws, size_t ws_size,
                              hipStream_t stream) {
    const float* g = (const float*)d_in[0];
    int* out = (int*)d_out;
    char* ws = (char*)d_ws;

    u64* best = (u64*)ws;                            // B*N*8 = 1 MB
    u32* keyw = (u32*)(ws + (size_t)4 * NN * 8);     // B*EPAD*4 = 1 MB

    k_keys<<<512, 256, 0, stream>>>(g, keyw, best);
    k_mst4<<<4, 1024, 0, stream>>>(keyw, best, out);
}